// Round 1
// 2509.319 us; speedup vs baseline: 1.0249x; 1.0249x over previous
//
#include <hip/hip_runtime.h>
#include <stdint.h>

#define B_ 16
#define S_ 30
#define T_ 10
#define H_ 400
#define V_ 20000
#define L_ 200
#define G_ 3
#define SB 480          // S*B rows
#define KP 416          // padded K (13*32)
#define MP 512          // padded M rows (8*64)
#define NT_VOC 313      // ceil(20000/64)
#define NP_G 1216       // padded 3H rows (19*64)
#define NP_EMB 20096    // padded V rows (314*64)
#define TV (T_*V_)      // 200000

typedef unsigned short ushort_t;
typedef __attribute__((ext_vector_type(8))) short frag8;     // 8 bf16
typedef __attribute__((ext_vector_type(4))) float f32x4;

__device__ __forceinline__ float b2f(ushort_t u){ return __uint_as_float(((unsigned)u)<<16); }
__device__ __forceinline__ ushort_t f2b(float f){
  unsigned u = __float_as_uint(f);
  unsigned r = u + 0x7fffu + ((u>>16)&1u);   // RNE
  return (ushort_t)(r>>16);
}

// ---------- split f32 weight (3H x H) -> hi/lo bf16 padded (NP_G x KP) ----------
__global__ void padsplit_kernel(const float* __restrict__ src,
                                ushort_t* __restrict__ hi, ushort_t* __restrict__ lo){
  int idx = blockIdx.x*256 + threadIdx.x;
  if (idx >= NP_G*KP) return;
  int r = idx / KP, c = idx - r*KP;
  ushort_t h = 0, l = 0;
  if (r < 3*H_ && c < H_){
    float v = src[r*H_ + c];
    h = f2b(v);
    l = f2b(v - b2f(h));
  }
  hi[idx] = h; lo[idx] = l;
}

// ---------- emb f32 (V x H) -> bf16 padded (NP_EMB x KP) ----------
__global__ void embcvt_kernel(const float* __restrict__ emb, ushort_t* __restrict__ dst){
  long long idx = (long long)blockIdx.x*256 + threadIdx.x;
  if (idx >= (long long)NP_EMB*KP) return;
  int r = (int)(idx / KP), c = (int)(idx - (long long)r*KP);
  ushort_t v = 0;
  if (r < V_ && c < H_) v = f2b(emb[(size_t)r*H_ + c]);
  dst[idx] = v;
}

// ---------- seq (B,L,H) -> seqT (B,H,L), LDS tile transpose ----------
__global__ __launch_bounds__(256) void transpose_kernel(
    const float* __restrict__ src, float* __restrict__ dst){
  __shared__ float tile[32][33];
  int b  = blockIdx.z;
  int l0 = blockIdx.x*32, k0 = blockIdx.y*32;
  int tx = threadIdx.x & 31, ty = threadIdx.x >> 5;   // 32 x 8
  const float* s = src + (size_t)b*L_*H_;
  float*       d = dst + (size_t)b*H_*L_;
  #pragma unroll
  for (int i=ty; i<32; i+=8){
    int l = l0+i, k = k0+tx;
    tile[i][tx] = (l<L_ && k<H_) ? s[(size_t)l*H_ + k] : 0.f;
  }
  __syncthreads();
  #pragma unroll
  for (int i=ty; i<32; i+=8){
    int k = k0+i, l = l0+tx;
    if (k<H_ && l<L_) d[(size_t)k*L_ + l] = tile[tx][i];
  }
}

// ---------- init: x0 = slot_emb bcast; hf = slot_att bcast; zero pads ----------
__global__ void init_kernel(const float* __restrict__ slot_att, const float* __restrict__ slot_emb,
                            float* __restrict__ xf, ushort_t* __restrict__ xbf, ushort_t* __restrict__ xbf2,
                            ushort_t* __restrict__ hbf, ushort_t* __restrict__ hbf2,
                            float* __restrict__ hf){
  int idx = blockIdx.x*256 + threadIdx.x;
  if (idx >= MP*KP) return;
  int r = idx/KP, c = idx - r*KP;
  ushort_t xh = 0, xl = 0;
  if (r < SB && c < H_){
    int s = r >> 4;
    float xv = slot_emb[s*H_ + c];
    xf[r*H_ + c] = xv;
    xh = f2b(xv); xl = f2b(xv - b2f(xh));
    hf[r*H_ + c] = slot_att[s*H_ + c];
  }
  xbf[idx] = xh; xbf2[idx] = xl;
  hbf[idx] = 0;  hbf2[idx] = 0;
}

// ---------- attention (fallback, uncoalesced score phase) ----------
__global__ __launch_bounds__(256) void attend_kernel(
    const float* __restrict__ seq, const float* __restrict__ musk,
    const float* __restrict__ cond, float* __restrict__ ctx, float* __restrict__ prob){
  __shared__ float hrow[H_];
  __shared__ float pl[L_];
  __shared__ float red[256];
  __shared__ float mv, sv;
  int r = blockIdx.x; int tid = threadIdx.x;
  int b = r & 15;
  for (int k=tid; k<H_; k+=256) hrow[k] = cond[(size_t)r*H_ + k];
  __syncthreads();
  float score = -3.0e38f;
  if (tid < L_){
    const float4* sp = (const float4*)(seq + ((size_t)b*L_ + tid)*H_);
    float acc = 0.f;
    for (int k=0; k<H_; k+=4){
      float4 v = sp[k>>2];
      acc += hrow[k]*v.x + hrow[k+1]*v.y + hrow[k+2]*v.z + hrow[k+3]*v.w;
    }
    score = acc + musk[b*L_ + tid];
  }
  red[tid] = score; __syncthreads();
  for (int s=128;s>0;s>>=1){ if(tid<s) red[tid]=fmaxf(red[tid],red[tid+s]); __syncthreads(); }
  if (tid==0) mv = red[0];
  __syncthreads();
  float e = (tid<L_) ? __expf(score-mv) : 0.f;
  red[tid] = e; __syncthreads();
  for (int s=128;s>0;s>>=1){ if(tid<s) red[tid]+=red[tid+s]; __syncthreads(); }
  if (tid==0) sv = red[0];
  __syncthreads();
  if (tid<L_){ float p = e/sv; pl[tid]=p; prob[(size_t)r*L_+tid]=p; }
  __syncthreads();
  for (int k=tid; k<H_; k+=256){
    float a = 0.f;
    const float* sp = seq + (size_t)b*L_*H_ + k;
    for (int l=0;l<L_;l++) a += pl[l]*sp[(size_t)l*H_];
    ctx[(size_t)r*H_ + k] = a;
  }
}

// ---------- attention v2: coalesced score phase via seqT, sys+user in one grid ----------
__global__ __launch_bounds__(256) void attend2_kernel(
    const float* __restrict__ seqS, const float* __restrict__ seqTS, const float* __restrict__ muskS,
    const float* __restrict__ seqU, const float* __restrict__ seqTU, const float* __restrict__ muskU,
    const float* __restrict__ cond,
    float* __restrict__ ctxS, float* __restrict__ probS,
    float* __restrict__ ctxU, float* __restrict__ probU){
  __shared__ float hrow[H_];
  __shared__ float pl[L_];
  __shared__ float red[256];
  __shared__ float mv, sv;
  int r0 = blockIdx.x;
  int which = (r0 >= SB) ? 1 : 0;
  int r = which ? r0 - SB : r0;
  const float* seq  = which ? seqU  : seqS;
  const float* seqT = which ? seqTU : seqTS;
  const float* musk = which ? muskU : muskS;
  float* ctx  = which ? ctxU  : ctxS;
  float* prob = which ? probU : probS;
  int tid = threadIdx.x;
  int b = r & 15;
  for (int k=tid; k<H_; k+=256) hrow[k] = cond[(size_t)r*H_ + k];
  __syncthreads();
  float score = -3.0e38f;
  if (tid < L_){
    // lane i reads seqT[b][k][l=i]: consecutive lanes -> consecutive addresses (coalesced)
    const float* sp = seqT + (size_t)b*H_*L_ + tid;
    float acc = 0.f;
    #pragma unroll 4
    for (int k=0; k<H_; k+=4){
      float4 hv = *(const float4*)(hrow + k);    // LDS b128 broadcast
      acc += hv.x*sp[(size_t)(k  )*L_];
      acc += hv.y*sp[(size_t)(k+1)*L_];
      acc += hv.z*sp[(size_t)(k+2)*L_];
      acc += hv.w*sp[(size_t)(k+3)*L_];
    }
    score = acc + musk[b*L_ + tid];
  }
  red[tid] = score; __syncthreads();
  for (int s=128;s>0;s>>=1){ if(tid<s) red[tid]=fmaxf(red[tid],red[tid+s]); __syncthreads(); }
  if (tid==0) mv = red[0];
  __syncthreads();
  float e = (tid<L_) ? __expf(score-mv) : 0.f;
  red[tid] = e; __syncthreads();
  for (int s=128;s>0;s>>=1){ if(tid<s) red[tid]+=red[tid+s]; __syncthreads(); }
  if (tid==0) sv = red[0];
  __syncthreads();
  if (tid<L_){ float p = e/sv; pl[tid]=p; prob[(size_t)r*L_+tid]=p; }
  __syncthreads();
  // ctx phase: lanes read consecutive k of seq[b][l][:] -> already coalesced
  for (int k=tid; k<H_; k+=256){
    float a = 0.f;
    const float* sp2 = seq + (size_t)b*L_*H_ + k;
    #pragma unroll 4
    for (int l=0;l<L_;l+=4){
      float4 p4 = *(const float4*)(pl + l);      // LDS b128 broadcast
      a += p4.x*sp2[(size_t)(l  )*H_];
      a += p4.y*sp2[(size_t)(l+1)*H_];
      a += p4.z*sp2[(size_t)(l+2)*H_];
      a += p4.w*sp2[(size_t)(l+3)*H_];
    }
    ctx[(size_t)r*H_ + k] = a;
  }
}

// ---------- h0 = ctx_s + ctx_u; refresh hi/lo bf16 ----------
__global__ void addh_kernel(const float* __restrict__ cs, const float* __restrict__ cu,
                            float* __restrict__ hf, ushort_t* __restrict__ hbf, ushort_t* __restrict__ hbf2){
  int idx = blockIdx.x*256 + threadIdx.x;
  if (idx >= SB*H_) return;
  int r = idx/H_, c = idx - r*H_;
  float v = cs[idx] + cu[idx];
  hf[idx] = v;
  ushort_t hb = f2b(v);
  hbf [r*KP + c] = hb;
  hbf2[r*KP + c] = f2b(v - b2f(hb));
}

// ---------- vocab GEMM (bf16 emb copy): f32 logits staged in out t-slice ----------
__global__ __launch_bounds__(256) void vocab_gemm_bf(
    const ushort_t* __restrict__ A, const ushort_t* __restrict__ Bm,
    float* __restrict__ outp){
  int tid = threadIdx.x;
  int wave = tid>>6, lane = tid&63;
  int q = lane>>4, ln = lane&15;
  int m_base = blockIdx.y*64 + wave*16;
  int n_base = blockIdx.x*64;
  const ushort_t* Arow = A + (size_t)(m_base + ln)*KP;
  f32x4 acc0={0,0,0,0}, acc1={0,0,0,0}, acc2={0,0,0,0}, acc3={0,0,0,0};
  for (int kk=0; kk<KP; kk+=32){
    int ko = kk + q*8;
    frag8 a  = *(const frag8*)(Arow + ko);
    frag8 b0 = *(const frag8*)(Bm + (size_t)(n_base +  0 + ln)*KP + ko);
    frag8 b1 = *(const frag8*)(Bm + (size_t)(n_base + 16 + ln)*KP + ko);
    frag8 b2 = *(const frag8*)(Bm + (size_t)(n_base + 32 + ln)*KP + ko);
    frag8 b3 = *(const frag8*)(Bm + (size_t)(n_base + 48 + ln)*KP + ko);
    acc0 = __builtin_amdgcn_mfma_f32_16x16x32_bf16(a,b0,acc0,0,0,0);
    acc1 = __builtin_amdgcn_mfma_f32_16x16x32_bf16(a,b1,acc1,0,0,0);
    acc2 = __builtin_amdgcn_mfma_f32_16x16x32_bf16(a,b2,acc2,0,0,0);
    acc3 = __builtin_amdgcn_mfma_f32_16x16x32_bf16(a,b3,acc3,0,0,0);
  }
  int mrow = m_base + q*4;
  #pragma unroll
  for (int nt=0; nt<4; nt++){
    f32x4 acc = (nt==0)?acc0:(nt==1)?acc1:(nt==2)?acc2:acc3;
    int n = n_base + nt*16 + ln;
    if (n >= V_) continue;
    #pragma unroll
    for (int i=0;i<4;i++){
      int m = mrow + i;
      if (m < SB) outp[(size_t)m*TV + n] = acc[i];
    }
  }
}

__device__ __forceinline__ frag8 load_cvt8(const float* p){
  float4 a = *(const float4*)p;
  float4 b = *(const float4*)(p+4);
  frag8 r;
  r[0]=(short)f2b(a.x); r[1]=(short)f2b(a.y); r[2]=(short)f2b(a.z); r[3]=(short)f2b(a.w);
  r[4]=(short)f2b(b.x); r[5]=(short)f2b(b.y); r[6]=(short)f2b(b.z); r[7]=(short)f2b(b.w);
  return r;
}

// ---------- vocab GEMM fallback: read emb f32 directly ----------
__global__ __launch_bounds__(256) void vocab_gemm_f32b(
    const ushort_t* __restrict__ A, const float* __restrict__ emb,
    float* __restrict__ outp){
  int tid = threadIdx.x;
  int wave = tid>>6, lane = tid&63;
  int q = lane>>4, ln = lane&15;
  int m_base = blockIdx.y*64 + wave*16;
  int n_base = blockIdx.x*64;
  const ushort_t* Arow = A + (size_t)(m_base + ln)*KP;
  int n0 = min(n_base +  0 + ln, V_-1);
  int n1 = min(n_base + 16 + ln, V_-1);
  int n2 = min(n_base + 32 + ln, V_-1);
  int n3 = min(n_base + 48 + ln, V_-1);
  const float* B0 = emb + (size_t)n0*H_;
  const float* B1 = emb + (size_t)n1*H_;
  const float* B2 = emb + (size_t)n2*H_;
  const float* B3 = emb + (size_t)n3*H_;
  f32x4 acc0={0,0,0,0}, acc1={0,0,0,0}, acc2={0,0,0,0}, acc3={0,0,0,0};
  for (int kk=0; kk<KP; kk+=32){
    int ko = kk + q*8;
    int safe = (ko < H_) ? ko : 0;    // A zero-pad kills the extra products
    frag8 a  = *(const frag8*)(Arow + ko);
    frag8 b0 = load_cvt8(B0 + safe);
    frag8 b1 = load_cvt8(B1 + safe);
    frag8 b2 = load_cvt8(B2 + safe);
    frag8 b3 = load_cvt8(B3 + safe);
    acc0 = __builtin_amdgcn_mfma_f32_16x16x32_bf16(a,b0,acc0,0,0,0);
    acc1 = __builtin_amdgcn_mfma_f32_16x16x32_bf16(a,b1,acc1,0,0,0);
    acc2 = __builtin_amdgcn_mfma_f32_16x16x32_bf16(a,b2,acc2,0,0,0);
    acc3 = __builtin_amdgcn_mfma_f32_16x16x32_bf16(a,b3,acc3,0,0,0);
  }
  int mrow = m_base + q*4;
  #pragma unroll
  for (int nt=0; nt<4; nt++){
    f32x4 acc = (nt==0)?acc0:(nt==1)?acc1:(nt==2)?acc2:acc3;
    int n = n_base + nt*16 + ln;
    if (n >= V_) continue;
    #pragma unroll
    for (int i=0;i<4;i++){
      int m = mrow + i;
      if (m < SB) outp[(size_t)m*TV + n] = acc[i];
    }
  }
}

// ---------- GRU GEMMs with hi/lo splits (drop lo*lo): f32-faithful ----------
__global__ __launch_bounds__(256) void grugemm_kernel(
    const ushort_t* __restrict__ xbf, const ushort_t* __restrict__ xbf2,
    const ushort_t* __restrict__ hbf, const ushort_t* __restrict__ hbf2,
    const ushort_t* __restrict__ Wih_hi, const ushort_t* __restrict__ Wih_lo,
    const ushort_t* __restrict__ Whh_hi, const ushort_t* __restrict__ Whh_lo,
    float* __restrict__ gi, float* __restrict__ gh){
  int tid = threadIdx.x;
  int wave = tid>>6, lane = tid&63;
  int q = lane>>4, ln = lane&15;
  int m_base = blockIdx.y*64 + wave*16;
  int n_base = blockIdx.x*64;
  const ushort_t* Ax  = xbf  + (size_t)(m_base + ln)*KP;
  const ushort_t* Ax2 = xbf2 + (size_t)(m_base + ln)*KP;
  const ushort_t* Ah  = hbf  + (size_t)(m_base + ln)*KP;
  const ushort_t* Ah2 = hbf2 + (size_t)(m_base + ln)*KP;
  f32x4 ai[4], ah[4];
  #pragma unroll
  for (int nt=0;nt<4;nt++){ ai[nt]=(f32x4){0,0,0,0}; ah[nt]=(f32x4){0,0,0,0}; }
  for (int kk=0; kk<KP; kk+=32){
    int ko = kk + q*8;
    frag8 ax  = *(const frag8*)(Ax  + ko);
    frag8 ax2 = *(const frag8*)(Ax2 + ko);
    frag8 ahv = *(const frag8*)(Ah  + ko);
    frag8 ah2 = *(const frag8*)(Ah2 + ko);
    #pragma unroll
    for (int nt=0;nt<4;nt++){
      size_t nrow = (size_t)(n_base + nt*16 + ln)*KP + ko;
      frag8 bih = *(const frag8*)(Wih_hi + nrow);
      frag8 bil = *(const frag8*)(Wih_lo + nrow);
      frag8 bhh = *(const frag8*)(Whh_hi + nrow);
      frag8 bhl = *(const frag8*)(Whh_lo + nrow);
      ai[nt] = __builtin_amdgcn_mfma_f32_16x16x32_bf16(ax, bih, ai[nt],0,0,0);
      ai[nt] = __builtin_amdgcn_mfma_f32_16x16x32_bf16(ax, bil, ai[nt],0,0,0);
      ai[nt] = __builtin_amdgcn_mfma_f32_16x16x32_bf16(ax2,bih, ai[nt],0,0,0);
      ah[nt] = __builtin_amdgcn_mfma_f32_16x16x32_bf16(ahv,bhh, ah[nt],0,0,0);
      ah[nt] = __builtin_amdgcn_mfma_f32_16x16x32_bf16(ahv,bhl, ah[nt],0,0,0);
      ah[nt] = __builtin_amdgcn_mfma_f32_16x16x32_bf16(ah2,bhh, ah[nt],0,0,0);
    }
  }
  int mrow = m_base + q*4;
  #pragma unroll
  for (int nt=0; nt<4; nt++){
    int n = n_base + nt*16 + ln;
    if (n >= 3*H_) continue;
    #pragma unroll
    for (int i=0;i<4;i++){
      int m = mrow + i;
      if (m < SB){
        gi[(size_t)m*(3*H_) + n] = ai[nt][i];
        gh[(size_t)m*(3*H_) + n] = ah[nt][i];
      }
    }
  }
}

// ---------- GRU pointwise ----------
__global__ void gru_kernel(const float* __restrict__ gi, const float* __restrict__ gh,
    const float* __restrict__ b_ih, const float* __restrict__ b_hh,
    float* __restrict__ hf, ushort_t* __restrict__ hbf, ushort_t* __restrict__ hbf2){
  int idx = blockIdx.x*256 + threadIdx.x;
  if (idx >= SB*H_) return;
  int r = idx/H_, j = idx - r*H_;
  const float* gir = gi + (size_t)r*(3*H_);
  const float* ghr = gh + (size_t)r*(3*H_);
  float i_r = gir[j]      + b_ih[j];
  float i_z = gir[H_+j]   + b_ih[H_+j];
  float i_n = gir[2*H_+j] + b_ih[2*H_+j];
  float h_r = ghr[j]      + b_hh[j];
  float h_z = ghr[H_+j]   + b_hh[H_+j];
  float h_n = ghr[2*H_+j] + b_hh[2*H_+j];
  float rg = 1.f/(1.f+__expf(-(i_r+h_r)));
  float zg = 1.f/(1.f+__expf(-(i_z+h_z)));
  float ng = tanhf(i_n + rg*h_n);
  float hv = (1.f-zg)*ng + zg*hf[idx];
  hf[idx] = hv;
  ushort_t hb = f2b(hv);
  hbf [r*KP + j] = hb;
  hbf2[r*KP + j] = f2b(hv - b2f(hb));
}

// ---------- per-row scalars ----------
__device__ __forceinline__ float block_reduce(float v, float* red, int tid){
  red[tid]=v; __syncthreads();
  for (int s=128;s>0;s>>=1){ if(tid<s) red[tid]+=red[tid+s]; __syncthreads(); }
  float r = red[0]; __syncthreads();
  return r;
}

__global__ __launch_bounds__(256) void small_kernel(
    const float* __restrict__ hf, const float* __restrict__ cs, const float* __restrict__ cu,
    const float* __restrict__ xf,
    const float* __restrict__ Wr_w, const float* __restrict__ Wr_b,
    const float* __restrict__ Wc_w, const float* __restrict__ Wc_b,
    const float* __restrict__ Wg_w, const float* __restrict__ Wg_b,
    float* __restrict__ sw_arr, float* __restrict__ ac_arr, float* __restrict__ bc_arr,
    float* __restrict__ gate_out, int do_gate){
  __shared__ float red[256];
  int r = blockIdx.x, tid = threadIdx.x;
  const float* h   = hf + (size_t)r*H_;
  const float* csr = cs + (size_t)r*H_;
  const float* cur = cu + (size_t)r*H_;
  const float* xr  = xf + (size_t)r*H_;
  float sr=0, ss=0, su=0, g0=0, g1=0, g2=0;
  for (int k=tid;k<4*H_;k+=256){
    float v = (k<H_)? h[k] : (k<2*H_)? csr[k-H_] : (k<3*H_)? cur[k-2*H_] : xr[k-3*H_];
    sr += Wr_w[k]*v;
  }
  for (int k=tid;k<3*H_;k+=256){
    float w = Wc_w[k];
    float vs = (k<H_)? h[k] : (k<2*H_)? csr[k-H_] : xr[k-2*H_];
    float vu = (k<H_)? h[k] : (k<2*H_)? cur[k-H_] : xr[k-2*H_];
    ss += w*vs; su += w*vu;
  }
  if (do_gate){
    for (int k=tid;k<2*H_;k+=256){
      float m = (k<H_)? csr[k] : cur[k-H_];
      g0 += Wg_w[k]*m;
      g1 += Wg_w[2*H_+k]*m;
      g2 += Wg_w[4*H_+k]*m;
    }
  }
  float SR = block_reduce(sr, red, tid);
  float SS = block_reduce(ss, red, tid);
  float SU = block_reduce(su, red, tid);
  float G0=0,G1=0,G2=0;
  if (do_gate){ G0=block_reduce(g0,red,tid); G1=block_reduce(g1,red,tid); G2=block_reduce(g2,red,tid); }
  if (tid==0){
    float swv = 1.f/(1.f+__expf(-(SR + Wr_b[0])));
    float lcs = SS + Wc_b[0];
    float lcu = SU + Wc_b[0];
    float mx = fmaxf(lcs,lcu);
    float es = __expf(lcs-mx), eu = __expf(lcu-mx);
    float al = es/(es+eu);
    sw_arr[r]=swv; ac_arr[r]=(1.f-swv)*al; bc_arr[r]=(1.f-swv)*(1.f-al);
    if (do_gate){
      gate_out[r*G_+0] = G0 + Wg_b[0];
      gate_out[r*G_+1] = G1 + Wg_b[1];
      gate_out[r*G_+2] = G2 + Wg_b[2];
    }
  }
}

// ---------- fused: softmax over staged logits + scale by sw + copy-dist scatter ----------
// one block per row; passes 2/3 over the 80KB row hit the XCD L2.
__global__ __launch_bounds__(256) void softmax_scatter_kernel(
    const float* __restrict__ sw_arr, const float* __restrict__ ac, const float* __restrict__ bc,
    const float* __restrict__ p_s, const float* __restrict__ p_u,
    const int* __restrict__ story_sys, const int* __restrict__ story_user,
    float* __restrict__ outp){
  __shared__ float red[256];
  __shared__ float Msh, Ssh;
  int r = blockIdx.x, tid = threadIdx.x;
  float* row = outp + (size_t)r*TV;
  float m = -3.0e38f;
  for (int v=tid; v<V_; v+=256) m = fmaxf(m, row[v]);
  red[tid]=m; __syncthreads();
  for (int s=128;s>0;s>>=1){ if(tid<s) red[tid]=fmaxf(red[tid],red[tid+s]); __syncthreads(); }
  if (tid==0) Msh = red[0];
  __syncthreads();
  float M = Msh;
  float sum = 0.f;
  for (int v=tid; v<V_; v+=256) sum += __expf(row[v] - M);
  red[tid]=sum; __syncthreads();
  for (int s=128;s>0;s>>=1){ if(tid<s) red[tid]+=red[tid+s]; __syncthreads(); }
  if (tid==0) Ssh = red[0];
  __syncthreads();
  float scale = sw_arr[r]/Ssh;
  for (int v=tid; v<V_; v+=256) row[v] = __expf(row[v] - M)*scale;
  __syncthreads();   // implicit vmcnt(0) drain: all scale-writes complete before atomics
  int b = r & 15;
  float a_ = ac[r], b_ = bc[r];
  for (int i=tid; i<2*L_; i+=256){
    int which = (i >= L_) ? 1 : 0;
    int l = which ? i - L_ : i;
    int v = which ? story_user[b*L_+l] : story_sys[b*L_+l];
    float val = which ? b_*p_u[(size_t)r*L_+l] : a_*p_s[(size_t)r*L_+l];
    atomicAdd(row + v, val);
  }
}

// ---------- x_next = emb[targets[b,s,t]] (f32 + hi/lo bf16) ----------
__global__ void nextx_kernel(const int* __restrict__ targets, const float* __restrict__ emb,
    float* __restrict__ xf, ushort_t* __restrict__ xbf, ushort_t* __restrict__ xbf2, int t){
  int idx = blockIdx.x*256 + threadIdx.x;
  if (idx >= SB*H_) return;
  int r = idx/H_, k = idx - r*H_;
  int s = r>>4, b = r&15;
  int tg = targets[(b*S_ + s)*T_ + t];
  float v = emb[(size_t)tg*H_ + k];
  xf[(size_t)r*H_ + k] = v;
  ushort_t hb = f2b(v);
  xbf [r*KP + k] = hb;
  xbf2[r*KP + k] = f2b(v - b2f(hb));
}

extern "C" void kernel_launch(void* const* d_in, const int* in_sizes, int n_in,
                              void* d_out, int out_size, void* d_ws, size_t ws_size,
                              hipStream_t stream){
  const float* sys_H    = (const float*)d_in[0];
  const float* user_H   = (const float*)d_in[1];
  const float* sys_musk = (const float*)d_in[2];
  const float* user_musk= (const float*)d_in[3];
  const float* emb      = (const float*)d_in[4];
  const float* W_ih     = (const float*)d_in[5];
  const float* W_hh     = (const float*)d_in[6];
  const float* b_ih     = (const float*)d_in[7];
  const float* b_hh     = (const float*)d_in[8];
  const float* Wg_w     = (const float*)d_in[9];
  const float* Wg_b     = (const float*)d_in[10];
  const float* Wr_w     = (const float*)d_in[11];
  const float* Wr_b     = (const float*)d_in[12];
  const float* Wc_w     = (const float*)d_in[13];
  const float* Wc_b     = (const float*)d_in[14];
  const float* slot_att = (const float*)d_in[15];
  const float* slot_emb = (const float*)d_in[16];
  const int* story_sys  = (const int*)d_in[17];
  const int* story_user = (const int*)d_in[18];
  const int* targets    = (const int*)d_in[19];
  float* out = (float*)d_out;                      // OUTPUT IS FLOAT32
  float* gate_out = out + (size_t)SB*TV;

  char* base = (char*)d_ws;
  size_t off = 0;
  auto take = [&](size_t bytes)->char*{
    char* p = base + off; off += (bytes + 255) & ~(size_t)255; return p;
  };
  ushort_t* Wih_hi = (ushort_t*)take((size_t)NP_G*KP*2);
  ushort_t* Wih_lo = (ushort_t*)take((size_t)NP_G*KP*2);
  ushort_t* Whh_hi = (ushort_t*)take((size_t)NP_G*KP*2);
  ushort_t* Whh_lo = (ushort_t*)take((size_t)NP_G*KP*2);
  ushort_t* hbf  = (ushort_t*)take((size_t)MP*KP*2);
  ushort_t* hbf2 = (ushort_t*)take((size_t)MP*KP*2);
  ushort_t* xbf  = (ushort_t*)take((size_t)MP*KP*2);
  ushort_t* xbf2 = (ushort_t*)take((size_t)MP*KP*2);
  float* hf    = (float*)take((size_t)SB*H_*4);
  float* xf    = (float*)take((size_t)SB*H_*4);
  float* ctx_s = (float*)take((size_t)SB*H_*4);
  float* ctx_u = (float*)take((size_t)SB*H_*4);
  float* p_s   = (float*)take((size_t)SB*L_*4);
  float* p_u   = (float*)take((size_t)SB*L_*4);
  float* gi    = (float*)take((size_t)SB*3*H_*4);
  float* gh    = (float*)take((size_t)SB*3*H_*4);
  float* sw_arr   = (float*)take(SB*4);
  float* ac_arr   = (float*)take(SB*4);
  float* bc_arr   = (float*)take(SB*4);
  // optional: bf16 emb copy (16.7 MB) if workspace allows
  int have_embp = (off + (size_t)NP_EMB*KP*2 + 512 <= ws_size) ? 1 : 0;
  ushort_t* embp = (ushort_t*)(have_embp ? take((size_t)NP_EMB*KP*2) : nullptr);
  // optional: transposed seq (B,H,L) x2 (102.4 MB) for coalesced attention scores
  size_t seqT_bytes = (size_t)B_*H_*L_*4;
  int have_seqT = (off + 2*((seqT_bytes+255)&~(size_t)255) <= ws_size) ? 1 : 0;
  float* seqT_s = (float*)(have_seqT ? take(seqT_bytes) : nullptr);
  float* seqT_u = (float*)(have_seqT ? take(seqT_bytes) : nullptr);

  padsplit_kernel<<<(NP_G*KP+255)/256,256,0,stream>>>(W_ih, Wih_hi, Wih_lo);
  padsplit_kernel<<<(NP_G*KP+255)/256,256,0,stream>>>(W_hh, Whh_hi, Whh_lo);
  if (have_embp)
    embcvt_kernel<<<(int)(((long long)NP_EMB*KP+255)/256),256,0,stream>>>(emb, embp);
  if (have_seqT){
    transpose_kernel<<<dim3((L_+31)/32,(H_+31)/32,B_),256,0,stream>>>(sys_H, seqT_s);
    transpose_kernel<<<dim3((L_+31)/32,(H_+31)/32,B_),256,0,stream>>>(user_H, seqT_u);
  }
  init_kernel<<<(MP*KP+255)/256,256,0,stream>>>(slot_att, slot_emb, xf, xbf, xbf2, hbf, hbf2, hf);

  auto attend_pair = [&](){
    if (have_seqT){
      attend2_kernel<<<2*SB,256,0,stream>>>(sys_H, seqT_s, sys_musk,
                                            user_H, seqT_u, user_musk,
                                            hf, ctx_s, p_s, ctx_u, p_u);
    } else {
      attend_kernel<<<SB,256,0,stream>>>(sys_H, sys_musk, hf, ctx_s, p_s);
      attend_kernel<<<SB,256,0,stream>>>(user_H, user_musk, hf, ctx_u, p_u);
    }
  };

  attend_pair();
  addh_kernel<<<(SB*H_+255)/256,256,0,stream>>>(ctx_s, ctx_u, hf, hbf, hbf2);

  for (int t=0; t<T_; t++){
    grugemm_kernel<<<dim3(NP_G/64, MP/64),256,0,stream>>>(xbf, xbf2, hbf, hbf2,
        Wih_hi, Wih_lo, Whh_hi, Whh_lo, gi, gh);
    gru_kernel<<<(SB*H_+255)/256,256,0,stream>>>(gi, gh, b_ih, b_hh, hf, hbf, hbf2);
    attend_pair();
    small_kernel<<<SB,256,0,stream>>>(hf, ctx_s, ctx_u, xf, Wr_w, Wr_b, Wc_w, Wc_b, Wg_w, Wg_b,
                                      sw_arr, ac_arr, bc_arr, gate_out, (t==0)?1:0);
    float* outp = out + (size_t)t*V_;   // f32 logits staged in-place in the t-slice
    if (have_embp)
      vocab_gemm_bf<<<dim3(NT_VOC, MP/64),256,0,stream>>>(hbf, embp, outp);
    else
      vocab_gemm_f32b<<<dim3(NT_VOC, MP/64),256,0,stream>>>(hbf, emb, outp);
    softmax_scatter_kernel<<<SB,256,0,stream>>>(sw_arr, ac_arr, bc_arr, p_s, p_u,
                                                story_sys, story_user, outp);
    if (t < T_-1)
      nextx_kernel<<<(SB*H_+255)/256,256,0,stream>>>(targets, emb, xf, xbf, xbf2, t);
  }
}

// Round 2
// 2169.083 us; speedup vs baseline: 1.1857x; 1.1569x over previous
//
#include <hip/hip_runtime.h>
#include <stdint.h>

#define B_ 16
#define S_ 30
#define T_ 10
#define H_ 400
#define V_ 20000
#define L_ 200
#define G_ 3
#define SB 480          // S*B rows
#define KP 416          // padded K (13*32)
#define MP 512          // padded M rows (8*64)
#define NT_VOC 313      // ceil(20000/64)
#define NP_G 1216       // padded 3H rows (19*64)
#define NP_EMB 20096    // padded V rows (314*64)
#define TV (T_*V_)      // 200000

// setup-mega role block counts
#define TT_TILES 1456   // 16 * 7 * 13 transpose tiles
#define PS_BLKS 1976    // NP_G*KP/256
#define EC_BLKS 32656   // NP_EMB*KP/256
#define INIT_BLKS 832   // MP*KP/256

typedef unsigned short ushort_t;
typedef __attribute__((ext_vector_type(8))) short frag8;     // 8 bf16
typedef __attribute__((ext_vector_type(4))) float f32x4;

__device__ __forceinline__ float b2f(ushort_t u){ return __uint_as_float(((unsigned)u)<<16); }
__device__ __forceinline__ ushort_t f2b(float f){
  unsigned u = __float_as_uint(f);
  unsigned r = u + 0x7fffu + ((u>>16)&1u);   // RNE
  return (ushort_t)(r>>16);
}

// ================= setup bodies (used by standalone + mega) =================

__device__ __forceinline__ void padsplit_body(const float* __restrict__ src,
    ushort_t* __restrict__ hi, ushort_t* __restrict__ lo, int idx){
  if (idx >= NP_G*KP) return;
  int r = idx / KP, c = idx - r*KP;
  ushort_t h = 0, l = 0;
  if (r < 3*H_ && c < H_){
    float v = src[r*H_ + c];
    h = f2b(v);
    l = f2b(v - b2f(h));
  }
  hi[idx] = h; lo[idx] = l;
}

__global__ void padsplit_kernel(const float* __restrict__ src,
                                ushort_t* __restrict__ hi, ushort_t* __restrict__ lo){
  padsplit_body(src, hi, lo, blockIdx.x*256 + threadIdx.x);
}

__device__ __forceinline__ void embcvt_body(const float* __restrict__ emb,
    ushort_t* __restrict__ dst, long long idx){
  if (idx >= (long long)NP_EMB*KP) return;
  int r = (int)(idx / KP), c = (int)(idx - (long long)r*KP);
  ushort_t v = 0;
  if (r < V_ && c < H_) v = f2b(emb[(size_t)r*H_ + c]);
  dst[idx] = v;
}

__global__ void embcvt_kernel(const float* __restrict__ emb, ushort_t* __restrict__ dst){
  embcvt_body(emb, dst, (long long)blockIdx.x*256 + threadIdx.x);
}

__device__ __forceinline__ void transpose_body(const float* __restrict__ src,
    float* __restrict__ dst, int rel, int tid, float (*tile)[33]){
  int b  = rel / 91;           // 7*13 tiles per b
  int rem = rel - b*91;
  int l0 = (rem % 7)*32, k0 = (rem / 7)*32;
  int tx = tid & 31, ty = tid >> 5;   // 32 x 8
  const float* s = src + (size_t)b*L_*H_;
  float*       d = dst + (size_t)b*H_*L_;
  #pragma unroll
  for (int i=ty; i<32; i+=8){
    int l = l0+i, k = k0+tx;
    tile[i][tx] = (l<L_ && k<H_) ? s[(size_t)l*H_ + k] : 0.f;
  }
  __syncthreads();
  #pragma unroll
  for (int i=ty; i<32; i+=8){
    int k = k0+i, l = l0+tx;
    if (k<H_ && l<L_) d[(size_t)k*L_ + l] = tile[tx][i];
  }
}

__global__ __launch_bounds__(256) void transpose_kernel(
    const float* __restrict__ src, float* __restrict__ dst){
  __shared__ float tile[32][33];
  int rel = blockIdx.z*91 + blockIdx.y*7 + blockIdx.x;   // not used in fallback form below
  (void)rel;
  // fallback standalone uses 3D grid mapping identical to mega's flattened one:
  int flat = (blockIdx.z*13 + blockIdx.y)*7 + blockIdx.x;
  transpose_body(src, dst, flat, threadIdx.x, tile);
}

__device__ __forceinline__ void init_body(const float* __restrict__ slot_att,
    const float* __restrict__ slot_emb,
    float* __restrict__ xf, ushort_t* __restrict__ xbf, ushort_t* __restrict__ xbf2,
    ushort_t* __restrict__ hbf, ushort_t* __restrict__ hbf2,
    float* __restrict__ hf, int idx){
  if (idx >= MP*KP) return;
  int r = idx/KP, c = idx - r*KP;
  ushort_t xh = 0, xl = 0;
  if (r < SB && c < H_){
    int s = r >> 4;
    float xv = slot_emb[s*H_ + c];
    xf[r*H_ + c] = xv;
    xh = f2b(xv); xl = f2b(xv - b2f(xh));
    hf[r*H_ + c] = slot_att[s*H_ + c];
  }
  xbf[idx] = xh; xbf2[idx] = xl;
  hbf[idx] = 0;  hbf2[idx] = 0;
}

__global__ void init_kernel(const float* __restrict__ slot_att, const float* __restrict__ slot_emb,
                            float* __restrict__ xf, ushort_t* __restrict__ xbf, ushort_t* __restrict__ xbf2,
                            ushort_t* __restrict__ hbf, ushort_t* __restrict__ hbf2,
                            float* __restrict__ hf){
  init_body(slot_att, slot_emb, xf, xbf, xbf2, hbf, hbf2, hf, blockIdx.x*256 + threadIdx.x);
}

// ---------- setup mega: all 6 independent setup jobs in one dispatch ----------
__global__ __launch_bounds__(256) void setup_mega_kernel(
    const float* __restrict__ sys_H, const float* __restrict__ user_H,
    float* __restrict__ seqT_s, float* __restrict__ seqT_u,
    const float* __restrict__ slot_att, const float* __restrict__ slot_emb,
    float* __restrict__ xf, ushort_t* __restrict__ xbf, ushort_t* __restrict__ xbf2,
    ushort_t* __restrict__ hbf, ushort_t* __restrict__ hbf2, float* __restrict__ hf,
    const float* __restrict__ W_ih, ushort_t* __restrict__ Wih_hi, ushort_t* __restrict__ Wih_lo,
    const float* __restrict__ W_hh, ushort_t* __restrict__ Whh_hi, ushort_t* __restrict__ Whh_lo,
    const float* __restrict__ emb, ushort_t* __restrict__ embp){
  __shared__ float tile[32][33];
  int bid = blockIdx.x, tid = threadIdx.x;
  if (bid < TT_TILES){
    transpose_body(sys_H, seqT_s, bid, tid, tile);
  } else if (bid < 2*TT_TILES){
    transpose_body(user_H, seqT_u, bid - TT_TILES, tid, tile);
  } else if (bid < 2*TT_TILES + INIT_BLKS){
    init_body(slot_att, slot_emb, xf, xbf, xbf2, hbf, hbf2, hf,
              (bid - 2*TT_TILES)*256 + tid);
  } else if (bid < 2*TT_TILES + INIT_BLKS + PS_BLKS){
    padsplit_body(W_ih, Wih_hi, Wih_lo, (bid - 2*TT_TILES - INIT_BLKS)*256 + tid);
  } else if (bid < 2*TT_TILES + INIT_BLKS + 2*PS_BLKS){
    padsplit_body(W_hh, Whh_hi, Whh_lo, (bid - 2*TT_TILES - INIT_BLKS - PS_BLKS)*256 + tid);
  } else {
    embcvt_body(emb, embp, (long long)(bid - 2*TT_TILES - INIT_BLKS - 2*PS_BLKS)*256 + tid);
  }
}

// ================= attention =================

// fallback (uncoalesced score phase)
__global__ __launch_bounds__(256) void attend_kernel(
    const float* __restrict__ seq, const float* __restrict__ musk,
    const float* __restrict__ cond, float* __restrict__ ctx, float* __restrict__ prob){
  __shared__ float hrow[H_];
  __shared__ float pl[L_];
  __shared__ float red[256];
  int r = blockIdx.x; int tid = threadIdx.x;
  int b = r & 15;
  for (int k=tid; k<H_; k+=256) hrow[k] = cond[(size_t)r*H_ + k];
  __syncthreads();
  float score = -3.0e38f;
  if (tid < L_){
    const float4* sp = (const float4*)(seq + ((size_t)b*L_ + tid)*H_);
    float acc = 0.f;
    for (int k=0; k<H_; k+=4){
      float4 v = sp[k>>2];
      acc += hrow[k]*v.x + hrow[k+1]*v.y + hrow[k+2]*v.z + hrow[k+3]*v.w;
    }
    score = acc + musk[b*L_ + tid];
  }
  red[tid] = score; __syncthreads();
  for (int s=128;s>0;s>>=1){ if(tid<s) red[tid]=fmaxf(red[tid],red[tid+s]); __syncthreads(); }
  float mv = red[0]; __syncthreads();
  float e = (tid<L_) ? __expf(score-mv) : 0.f;
  red[tid] = e; __syncthreads();
  for (int s=128;s>0;s>>=1){ if(tid<s) red[tid]+=red[tid+s]; __syncthreads(); }
  float sv = red[0]; __syncthreads();
  if (tid<L_){ float p = e/sv; pl[tid]=p; prob[(size_t)r*L_+tid]=p; }
  __syncthreads();
  for (int k=tid; k<H_; k+=256){
    float a = 0.f;
    const float* sp = seq + (size_t)b*L_*H_ + k;
    for (int l=0;l<L_;l++) a += pl[l]*sp[(size_t)l*H_];
    ctx[(size_t)r*H_ + k] = a;
  }
}

// coalesced attend body (score via seqT), shared arrays passed in
__device__ __forceinline__ void attend_body(
    int r0,
    const float* __restrict__ seqS, const float* __restrict__ seqTS, const float* __restrict__ muskS,
    const float* __restrict__ seqU, const float* __restrict__ seqTU, const float* __restrict__ muskU,
    const float* __restrict__ cond,
    float* __restrict__ ctxS, float* __restrict__ probS,
    float* __restrict__ ctxU, float* __restrict__ probU,
    float* hrow, float* pl, float* red){
  int which = (r0 >= SB) ? 1 : 0;
  int r = which ? r0 - SB : r0;
  const float* seq  = which ? seqU  : seqS;
  const float* seqT = which ? seqTU : seqTS;
  const float* musk = which ? muskU : muskS;
  float* ctx  = which ? ctxU  : ctxS;
  float* prob = which ? probU : probS;
  int tid = threadIdx.x;
  int b = r & 15;
  for (int k=tid; k<H_; k+=256) hrow[k] = cond[(size_t)r*H_ + k];
  __syncthreads();
  float score = -3.0e38f;
  if (tid < L_){
    const float* sp = seqT + (size_t)b*H_*L_ + tid;
    float acc = 0.f;
    #pragma unroll 4
    for (int k=0; k<H_; k+=4){
      float4 hv = *(const float4*)(hrow + k);
      acc += hv.x*sp[(size_t)(k  )*L_];
      acc += hv.y*sp[(size_t)(k+1)*L_];
      acc += hv.z*sp[(size_t)(k+2)*L_];
      acc += hv.w*sp[(size_t)(k+3)*L_];
    }
    score = acc + musk[b*L_ + tid];
  }
  red[tid] = score; __syncthreads();
  for (int s=128;s>0;s>>=1){ if(tid<s) red[tid]=fmaxf(red[tid],red[tid+s]); __syncthreads(); }
  float mv = red[0]; __syncthreads();
  float e = (tid<L_) ? __expf(score-mv) : 0.f;
  red[tid] = e; __syncthreads();
  for (int s=128;s>0;s>>=1){ if(tid<s) red[tid]+=red[tid+s]; __syncthreads(); }
  float sv = red[0]; __syncthreads();
  if (tid<L_){ float p = e/sv; pl[tid]=p; prob[(size_t)r*L_+tid]=p; }
  __syncthreads();
  for (int k=tid; k<H_; k+=256){
    float a = 0.f;
    const float* sp2 = seq + (size_t)b*L_*H_ + k;
    #pragma unroll 4
    for (int l=0;l<L_;l+=4){
      float4 p4 = *(const float4*)(pl + l);
      a += p4.x*sp2[(size_t)(l  )*H_];
      a += p4.y*sp2[(size_t)(l+1)*H_];
      a += p4.z*sp2[(size_t)(l+2)*H_];
      a += p4.w*sp2[(size_t)(l+3)*H_];
    }
    ctx[(size_t)r*H_ + k] = a;
  }
}

// standalone attend2 (used for h0 before the loop)
__global__ __launch_bounds__(256) void attend2_kernel(
    const float* __restrict__ seqS, const float* __restrict__ seqTS, const float* __restrict__ muskS,
    const float* __restrict__ seqU, const float* __restrict__ seqTU, const float* __restrict__ muskU,
    const float* __restrict__ cond,
    float* __restrict__ ctxS, float* __restrict__ probS,
    float* __restrict__ ctxU, float* __restrict__ probU){
  __shared__ float hrow[H_];
  __shared__ float pl[L_];
  __shared__ float red[256];
  attend_body(blockIdx.x, seqS, seqTS, muskS, seqU, seqTU, muskU, cond,
              ctxS, probS, ctxU, probU, hrow, pl, red);
}

// ---------- h0 = ctx_s + ctx_u; refresh hi/lo bf16 ----------
__global__ void addh_kernel(const float* __restrict__ cs, const float* __restrict__ cu,
                            float* __restrict__ hf, ushort_t* __restrict__ hbf, ushort_t* __restrict__ hbf2){
  int idx = blockIdx.x*256 + threadIdx.x;
  if (idx >= SB*H_) return;
  int r = idx/H_, c = idx - r*H_;
  float v = cs[idx] + cu[idx];
  hf[idx] = v;
  ushort_t hb = f2b(v);
  hbf [r*KP + c] = hb;
  hbf2[r*KP + c] = f2b(v - b2f(hb));
}

// ================= mega: attend (blocks [0,960)) + vocab GEMM w/ online-softmax partials =================
__global__ __launch_bounds__(256) void mega_kernel(
    const float* __restrict__ seqS, const float* __restrict__ seqTS, const float* __restrict__ muskS,
    const float* __restrict__ seqU, const float* __restrict__ seqTU, const float* __restrict__ muskU,
    const float* __restrict__ cond,
    float* __restrict__ ctxS, float* __restrict__ probS,
    float* __restrict__ ctxU, float* __restrict__ probU,
    const ushort_t* __restrict__ A, const ushort_t* __restrict__ Bm,
    float* __restrict__ outp, float* __restrict__ pmax, float* __restrict__ psum){
  __shared__ float hrow[H_];
  __shared__ float pl[L_];
  __shared__ float red[256];
  int tid = threadIdx.x;
  if (blockIdx.x < 2*SB){
    attend_body(blockIdx.x, seqS, seqTS, muskS, seqU, seqTU, muskU, cond,
                ctxS, probS, ctxU, probU, hrow, pl, red);
    return;
  }
  int vb = blockIdx.x - 2*SB;
  int nb = vb % NT_VOC, mb = vb / NT_VOC;
  int wave = tid>>6, lane = tid&63;
  int q = lane>>4, ln = lane&15;
  int m_base = mb*64 + wave*16;
  int n_base = nb*64;
  const ushort_t* Arow = A + (size_t)(m_base + ln)*KP;
  f32x4 acc[4];
  #pragma unroll
  for (int nt=0;nt<4;nt++) acc[nt]=(f32x4){0,0,0,0};
  for (int kk=0; kk<KP; kk+=32){
    int ko = kk + q*8;
    frag8 a  = *(const frag8*)(Arow + ko);
    #pragma unroll
    for (int nt=0;nt<4;nt++){
      frag8 b = *(const frag8*)(Bm + (size_t)(n_base + nt*16 + ln)*KP + ko);
      acc[nt] = __builtin_amdgcn_mfma_f32_16x16x32_bf16(a,b,acc[nt],0,0,0);
    }
  }
  int mrow = m_base + q*4;
  // write logits
  #pragma unroll
  for (int nt=0; nt<4; nt++){
    int n = n_base + nt*16 + ln;
    if (n >= V_) continue;
    #pragma unroll
    for (int i=0;i<4;i++){
      int m = mrow + i;
      if (m < SB) outp[(size_t)m*TV + n] = acc[nt][i];
    }
  }
  // per-block online-softmax partials: row max + sum(exp(x - max)) over this 64-col block
  #pragma unroll
  for (int i=0;i<4;i++){
    float mx = -3.0e38f;
    #pragma unroll
    for (int nt=0;nt<4;nt++){
      int n = n_base + nt*16 + ln;
      if (n < V_) mx = fmaxf(mx, acc[nt][i]);
    }
    #pragma unroll
    for (int d=8; d>=1; d>>=1) mx = fmaxf(mx, __shfl_xor(mx, d));
    float sm = 0.f;
    #pragma unroll
    for (int nt=0;nt<4;nt++){
      int n = n_base + nt*16 + ln;
      if (n < V_) sm += __expf(acc[nt][i] - mx);
    }
    #pragma unroll
    for (int d=8; d>=1; d>>=1) sm += __shfl_xor(sm, d);
    int m = mrow + i;
    if (ln == 0 && m < SB){
      pmax[(size_t)m*NT_VOC + nb] = mx;
      psum[(size_t)m*NT_VOC + nb] = sm;
    }
  }
}

// ---------- vocab GEMM fallback: read emb f32 directly (old 3-pass path) ----------
__device__ __forceinline__ frag8 load_cvt8(const float* p){
  float4 a = *(const float4*)p;
  float4 b = *(const float4*)(p+4);
  frag8 r;
  r[0]=(short)f2b(a.x); r[1]=(short)f2b(a.y); r[2]=(short)f2b(a.z); r[3]=(short)f2b(a.w);
  r[4]=(short)f2b(b.x); r[5]=(short)f2b(b.y); r[6]=(short)f2b(b.z); r[7]=(short)f2b(b.w);
  return r;
}

__global__ __launch_bounds__(256) void vocab_gemm_f32b(
    const ushort_t* __restrict__ A, const float* __restrict__ emb,
    float* __restrict__ outp){
  int tid = threadIdx.x;
  int wave = tid>>6, lane = tid&63;
  int q = lane>>4, ln = lane&15;
  int m_base = blockIdx.y*64 + wave*16;
  int n_base = blockIdx.x*64;
  const ushort_t* Arow = A + (size_t)(m_base + ln)*KP;
  int n0 = min(n_base +  0 + ln, V_-1);
  int n1 = min(n_base + 16 + ln, V_-1);
  int n2 = min(n_base + 32 + ln, V_-1);
  int n3 = min(n_base + 48 + ln, V_-1);
  const float* B0 = emb + (size_t)n0*H_;
  const float* B1 = emb + (size_t)n1*H_;
  const float* B2 = emb + (size_t)n2*H_;
  const float* B3 = emb + (size_t)n3*H_;
  f32x4 acc0={0,0,0,0}, acc1={0,0,0,0}, acc2={0,0,0,0}, acc3={0,0,0,0};
  for (int kk=0; kk<KP; kk+=32){
    int ko = kk + q*8;
    int safe = (ko < H_) ? ko : 0;
    frag8 a  = *(const frag8*)(Arow + ko);
    frag8 b0 = load_cvt8(B0 + safe);
    frag8 b1 = load_cvt8(B1 + safe);
    frag8 b2 = load_cvt8(B2 + safe);
    frag8 b3 = load_cvt8(B3 + safe);
    acc0 = __builtin_amdgcn_mfma_f32_16x16x32_bf16(a,b0,acc0,0,0,0);
    acc1 = __builtin_amdgcn_mfma_f32_16x16x32_bf16(a,b1,acc1,0,0,0);
    acc2 = __builtin_amdgcn_mfma_f32_16x16x32_bf16(a,b2,acc2,0,0,0);
    acc3 = __builtin_amdgcn_mfma_f32_16x16x32_bf16(a,b3,acc3,0,0,0);
  }
  int mrow = m_base + q*4;
  #pragma unroll
  for (int nt=0; nt<4; nt++){
    f32x4 acc = (nt==0)?acc0:(nt==1)?acc1:(nt==2)?acc2:acc3;
    int n = n_base + nt*16 + ln;
    if (n >= V_) continue;
    #pragma unroll
    for (int i=0;i<4;i++){
      int m = mrow + i;
      if (m < SB) outp[(size_t)m*TV + n] = acc[i];
    }
  }
}

// ================= GRU GEMMs =================
__global__ __launch_bounds__(256) void grugemm_kernel(
    const ushort_t* __restrict__ xbf, const ushort_t* __restrict__ xbf2,
    const ushort_t* __restrict__ hbf, const ushort_t* __restrict__ hbf2,
    const ushort_t* __restrict__ Wih_hi, const ushort_t* __restrict__ Wih_lo,
    const ushort_t* __restrict__ Whh_hi, const ushort_t* __restrict__ Whh_lo,
    float* __restrict__ gi, float* __restrict__ gh){
  int tid = threadIdx.x;
  int wave = tid>>6, lane = tid&63;
  int q = lane>>4, ln = lane&15;
  int m_base = blockIdx.y*64 + wave*16;
  int n_base = blockIdx.x*64;
  const ushort_t* Ax  = xbf  + (size_t)(m_base + ln)*KP;
  const ushort_t* Ax2 = xbf2 + (size_t)(m_base + ln)*KP;
  const ushort_t* Ah  = hbf  + (size_t)(m_base + ln)*KP;
  const ushort_t* Ah2 = hbf2 + (size_t)(m_base + ln)*KP;
  f32x4 ai[4], ah[4];
  #pragma unroll
  for (int nt=0;nt<4;nt++){ ai[nt]=(f32x4){0,0,0,0}; ah[nt]=(f32x4){0,0,0,0}; }
  for (int kk=0; kk<KP; kk+=32){
    int ko = kk + q*8;
    frag8 ax  = *(const frag8*)(Ax  + ko);
    frag8 ax2 = *(const frag8*)(Ax2 + ko);
    frag8 ahv = *(const frag8*)(Ah  + ko);
    frag8 ah2 = *(const frag8*)(Ah2 + ko);
    #pragma unroll
    for (int nt=0;nt<4;nt++){
      size_t nrow = (size_t)(n_base + nt*16 + ln)*KP + ko;
      frag8 bih = *(const frag8*)(Wih_hi + nrow);
      frag8 bil = *(const frag8*)(Wih_lo + nrow);
      frag8 bhh = *(const frag8*)(Whh_hi + nrow);
      frag8 bhl = *(const frag8*)(Whh_lo + nrow);
      ai[nt] = __builtin_amdgcn_mfma_f32_16x16x32_bf16(ax, bih, ai[nt],0,0,0);
      ai[nt] = __builtin_amdgcn_mfma_f32_16x16x32_bf16(ax, bil, ai[nt],0,0,0);
      ai[nt] = __builtin_amdgcn_mfma_f32_16x16x32_bf16(ax2,bih, ai[nt],0,0,0);
      ah[nt] = __builtin_amdgcn_mfma_f32_16x16x32_bf16(ahv,bhh, ah[nt],0,0,0);
      ah[nt] = __builtin_amdgcn_mfma_f32_16x16x32_bf16(ahv,bhl, ah[nt],0,0,0);
      ah[nt] = __builtin_amdgcn_mfma_f32_16x16x32_bf16(ah2,bhh, ah[nt],0,0,0);
    }
  }
  int mrow = m_base + q*4;
  #pragma unroll
  for (int nt=0; nt<4; nt++){
    int n = n_base + nt*16 + ln;
    if (n >= 3*H_) continue;
    #pragma unroll
    for (int i=0;i<4;i++){
      int m = mrow + i;
      if (m < SB){
        gi[(size_t)m*(3*H_) + n] = ai[nt][i];
        gh[(size_t)m*(3*H_) + n] = ah[nt][i];
      }
    }
  }
}

// ---------- GRU pointwise ----------
__global__ void gru_kernel(const float* __restrict__ gi, const float* __restrict__ gh,
    const float* __restrict__ b_ih, const float* __restrict__ b_hh,
    float* __restrict__ hf, ushort_t* __restrict__ hbf, ushort_t* __restrict__ hbf2){
  int idx = blockIdx.x*256 + threadIdx.x;
  if (idx >= SB*H_) return;
  int r = idx/H_, j = idx - r*H_;
  const float* gir = gi + (size_t)r*(3*H_);
  const float* ghr = gh + (size_t)r*(3*H_);
  float i_r = gir[j]      + b_ih[j];
  float i_z = gir[H_+j]   + b_ih[H_+j];
  float i_n = gir[2*H_+j] + b_ih[2*H_+j];
  float h_r = ghr[j]      + b_hh[j];
  float h_z = ghr[H_+j]   + b_hh[H_+j];
  float h_n = ghr[2*H_+j] + b_hh[2*H_+j];
  float rg = 1.f/(1.f+__expf(-(i_r+h_r)));
  float zg = 1.f/(1.f+__expf(-(i_z+h_z)));
  float ng = tanhf(i_n + rg*h_n);
  float hv = (1.f-zg)*ng + zg*hf[idx];
  hf[idx] = hv;
  ushort_t hb = f2b(hv);
  hbf [r*KP + j] = hb;
  hbf2[r*KP + j] = f2b(hv - b2f(hb));
}

// ================= per-row tail =================
__device__ __forceinline__ float block_reduce(float v, float* red, int tid){
  red[tid]=v; __syncthreads();
  for (int s=128;s>0;s>>=1){ if(tid<s) red[tid]+=red[tid+s]; __syncthreads(); }
  float r = red[0]; __syncthreads();
  return r;
}

// fallback small kernel (old path)
__global__ __launch_bounds__(256) void small_kernel(
    const float* __restrict__ hf, const float* __restrict__ cs, const float* __restrict__ cu,
    const float* __restrict__ xf,
    const float* __restrict__ Wr_w, const float* __restrict__ Wr_b,
    const float* __restrict__ Wc_w, const float* __restrict__ Wc_b,
    const float* __restrict__ Wg_w, const float* __restrict__ Wg_b,
    float* __restrict__ sw_arr, float* __restrict__ ac_arr, float* __restrict__ bc_arr,
    float* __restrict__ gate_out, int do_gate){
  __shared__ float red[256];
  int r = blockIdx.x, tid = threadIdx.x;
  const float* h   = hf + (size_t)r*H_;
  const float* csr = cs + (size_t)r*H_;
  const float* cur = cu + (size_t)r*H_;
  const float* xr  = xf + (size_t)r*H_;
  float sr=0, ss=0, su=0, g0=0, g1=0, g2=0;
  for (int k=tid;k<4*H_;k+=256){
    float v = (k<H_)? h[k] : (k<2*H_)? csr[k-H_] : (k<3*H_)? cur[k-2*H_] : xr[k-3*H_];
    sr += Wr_w[k]*v;
  }
  for (int k=tid;k<3*H_;k+=256){
    float w = Wc_w[k];
    float vs = (k<H_)? h[k] : (k<2*H_)? csr[k-H_] : xr[k-2*H_];
    float vu = (k<H_)? h[k] : (k<2*H_)? cur[k-H_] : xr[k-2*H_];
    ss += w*vs; su += w*vu;
  }
  if (do_gate){
    for (int k=tid;k<2*H_;k+=256){
      float m = (k<H_)? csr[k] : cur[k-H_];
      g0 += Wg_w[k]*m;
      g1 += Wg_w[2*H_+k]*m;
      g2 += Wg_w[4*H_+k]*m;
    }
  }
  float SR = block_reduce(sr, red, tid);
  float SS = block_reduce(ss, red, tid);
  float SU = block_reduce(su, red, tid);
  float G0=0,G1=0,G2=0;
  if (do_gate){ G0=block_reduce(g0,red,tid); G1=block_reduce(g1,red,tid); G2=block_reduce(g2,red,tid); }
  if (tid==0){
    float swv = 1.f/(1.f+__expf(-(SR + Wr_b[0])));
    float lcs = SS + Wc_b[0];
    float lcu = SU + Wc_b[0];
    float mx = fmaxf(lcs,lcu);
    float es = __expf(lcs-mx), eu = __expf(lcu-mx);
    float al = es/(es+eu);
    sw_arr[r]=swv; ac_arr[r]=(1.f-swv)*al; bc_arr[r]=(1.f-swv)*(1.f-al);
    if (do_gate){
      gate_out[r*G_+0] = G0 + Wg_b[0];
      gate_out[r*G_+1] = G1 + Wg_b[1];
      gate_out[r*G_+2] = G2 + Wg_b[2];
    }
  }
}

// fallback fused softmax+scatter (3-pass, old path)
__global__ __launch_bounds__(256) void softmax_scatter_kernel(
    const float* __restrict__ sw_arr, const float* __restrict__ ac, const float* __restrict__ bc,
    const float* __restrict__ p_s, const float* __restrict__ p_u,
    const int* __restrict__ story_sys, const int* __restrict__ story_user,
    float* __restrict__ outp){
  __shared__ float red[256];
  int r = blockIdx.x, tid = threadIdx.x;
  float* row = outp + (size_t)r*TV;
  float m = -3.0e38f;
  for (int v=tid; v<V_; v+=256) m = fmaxf(m, row[v]);
  red[tid]=m; __syncthreads();
  for (int s=128;s>0;s>>=1){ if(tid<s) red[tid]=fmaxf(red[tid],red[tid+s]); __syncthreads(); }
  float M = red[0]; __syncthreads();
  float sum = 0.f;
  for (int v=tid; v<V_; v+=256) sum += __expf(row[v] - M);
  red[tid]=sum; __syncthreads();
  for (int s=128;s>0;s>>=1){ if(tid<s) red[tid]+=red[tid+s]; __syncthreads(); }
  float S = red[0]; __syncthreads();
  float scale = sw_arr[r]/S;
  for (int v=tid; v<V_; v+=256) row[v] = __expf(row[v] - M)*scale;
  __syncthreads();
  int b = r & 15;
  float a_ = ac[r], b_ = bc[r];
  for (int i=tid; i<2*L_; i+=256){
    int which = (i >= L_) ? 1 : 0;
    int l = which ? i - L_ : i;
    int v = which ? story_user[b*L_+l] : story_sys[b*L_+l];
    float val = which ? b_*p_u[(size_t)r*L_+l] : a_*p_s[(size_t)r*L_+l];
    atomicAdd(row + v, val);
  }
}

// fallback nextx
__global__ void nextx_kernel(const int* __restrict__ targets, const float* __restrict__ emb,
    float* __restrict__ xf, ushort_t* __restrict__ xbf, ushort_t* __restrict__ xbf2, int t){
  int idx = blockIdx.x*256 + threadIdx.x;
  if (idx >= SB*H_) return;
  int r = idx/H_, k = idx - r*H_;
  int s = r>>4, b = r&15;
  int tg = targets[(b*S_ + s)*T_ + t];
  float v = emb[(size_t)tg*H_ + k];
  xf[(size_t)r*H_ + k] = v;
  ushort_t hb = f2b(v);
  xbf [r*KP + k] = hb;
  xbf2[r*KP + k] = f2b(v - b2f(hb));
}

// ---------- final fused tail: small scalars + stats from partials + finalize + scatter + nextx ----------
__global__ __launch_bounds__(256) void final_kernel(
    const float* __restrict__ hf, const float* __restrict__ cs, const float* __restrict__ cu,
    const float* __restrict__ Wr_w, const float* __restrict__ Wr_b,
    const float* __restrict__ Wc_w, const float* __restrict__ Wc_b,
    const float* __restrict__ Wg_w, const float* __restrict__ Wg_b,
    const float* __restrict__ pmax, const float* __restrict__ psum,
    const float* __restrict__ p_s, const float* __restrict__ p_u,
    const int* __restrict__ story_sys, const int* __restrict__ story_user,
    float* __restrict__ outp, float* __restrict__ gate_out, int do_gate,
    const int* __restrict__ targets, const float* __restrict__ emb,
    float* __restrict__ xf, ushort_t* __restrict__ xbf, ushort_t* __restrict__ xbf2,
    int t, int do_nextx){
  __shared__ float red[256];
  __shared__ float sh_sw, sh_ac, sh_bc;
  int r = blockIdx.x, tid = threadIdx.x;
  const float* h   = hf + (size_t)r*H_;
  const float* csr = cs + (size_t)r*H_;
  const float* cur = cu + (size_t)r*H_;
  const float* xr  = xf + (size_t)r*H_;
  // ---- per-row scalar dot products (small_kernel body) ----
  float sr=0, ss=0, su=0, g0=0, g1=0, g2=0;
  for (int k=tid;k<4*H_;k+=256){
    float v = (k<H_)? h[k] : (k<2*H_)? csr[k-H_] : (k<3*H_)? cur[k-2*H_] : xr[k-3*H_];
    sr += Wr_w[k]*v;
  }
  for (int k=tid;k<3*H_;k+=256){
    float w = Wc_w[k];
    float vs = (k<H_)? h[k] : (k<2*H_)? csr[k-H_] : xr[k-2*H_];
    float vu = (k<H_)? h[k] : (k<2*H_)? cur[k-H_] : xr[k-2*H_];
    ss += w*vs; su += w*vu;
  }
  if (do_gate){
    for (int k=tid;k<2*H_;k+=256){
      float m = (k<H_)? csr[k] : cur[k-H_];
      g0 += Wg_w[k]*m;
      g1 += Wg_w[2*H_+k]*m;
      g2 += Wg_w[4*H_+k]*m;
    }
  }
  float SR = block_reduce(sr, red, tid);
  float SS = block_reduce(ss, red, tid);
  float SU = block_reduce(su, red, tid);
  if (do_gate){
    float G0=block_reduce(g0,red,tid);
    float G1=block_reduce(g1,red,tid);
    float G2=block_reduce(g2,red,tid);
    if (tid==0){
      gate_out[r*G_+0] = G0 + Wg_b[0];
      gate_out[r*G_+1] = G1 + Wg_b[1];
      gate_out[r*G_+2] = G2 + Wg_b[2];
    }
  }
  if (tid==0){
    float swv = 1.f/(1.f+__expf(-(SR + Wr_b[0])));
    float lcs = SS + Wc_b[0];
    float lcu = SU + Wc_b[0];
    float mx = fmaxf(lcs,lcu);
    float es = __expf(lcs-mx), eu = __expf(lcu-mx);
    float al = es/(es+eu);
    sh_sw = swv; sh_ac = (1.f-swv)*al; sh_bc = (1.f-swv)*(1.f-al);
  }
  __syncthreads();
  // ---- combine online-softmax partials -> row max M and denom S ----
  const float* pmr = pmax + (size_t)r*NT_VOC;
  const float* psr = psum + (size_t)r*NT_VOC;
  float lm = -3.0e38f;
  for (int nb=tid; nb<NT_VOC; nb+=256) lm = fmaxf(lm, pmr[nb]);
  red[tid]=lm; __syncthreads();
  for (int s=128;s>0;s>>=1){ if(tid<s) red[tid]=fmaxf(red[tid],red[tid+s]); __syncthreads(); }
  float M = red[0]; __syncthreads();
  float ls = 0.f;
  for (int nb=tid; nb<NT_VOC; nb+=256) ls += psr[nb]*__expf(pmr[nb]-M);
  float S = block_reduce(ls, red, tid);
  // ---- single read-modify-write pass: p = sw * softmax ----
  float scale = sh_sw / S;
  float* row = outp + (size_t)r*TV;
  for (int v=tid; v<V_; v+=256) row[v] = __expf(row[v]-M)*scale;
  __syncthreads();    // drain scale-writes before atomics
  // ---- copy-dist scatter ----
  int b = r & 15;
  float a_ = sh_ac, b_ = sh_bc;
  for (int i=tid; i<2*L_; i+=256){
    int which = (i >= L_) ? 1 : 0;
    int l = which ? i - L_ : i;
    int v = which ? story_user[b*L_+l] : story_sys[b*L_+l];
    float val = which ? b_*p_u[(size_t)r*L_+l] : a_*p_s[(size_t)r*L_+l];
    atomicAdd(row + v, val);
  }
  // ---- x_next = emb[targets[b,s,t]] (xf row r read above; barrier-ordered) ----
  if (do_nextx){
    int s = r>>4;
    int tg = targets[(b*S_ + s)*T_ + t];
    for (int k=tid; k<H_; k+=256){
      float v = emb[(size_t)tg*H_ + k];
      xf[(size_t)r*H_ + k] = v;
      ushort_t hb = f2b(v);
      xbf [r*KP + k] = hb;
      xbf2[r*KP + k] = f2b(v - b2f(hb));
    }
  }
}

extern "C" void kernel_launch(void* const* d_in, const int* in_sizes, int n_in,
                              void* d_out, int out_size, void* d_ws, size_t ws_size,
                              hipStream_t stream){
  const float* sys_H    = (const float*)d_in[0];
  const float* user_H   = (const float*)d_in[1];
  const float* sys_musk = (const float*)d_in[2];
  const float* user_musk= (const float*)d_in[3];
  const float* emb      = (const float*)d_in[4];
  const float* W_ih     = (const float*)d_in[5];
  const float* W_hh     = (const float*)d_in[6];
  const float* b_ih     = (const float*)d_in[7];
  const float* b_hh     = (const float*)d_in[8];
  const float* Wg_w     = (const float*)d_in[9];
  const float* Wg_b     = (const float*)d_in[10];
  const float* Wr_w     = (const float*)d_in[11];
  const float* Wr_b     = (const float*)d_in[12];
  const float* Wc_w     = (const float*)d_in[13];
  const float* Wc_b     = (const float*)d_in[14];
  const float* slot_att = (const float*)d_in[15];
  const float* slot_emb = (const float*)d_in[16];
  const int* story_sys  = (const int*)d_in[17];
  const int* story_user = (const int*)d_in[18];
  const int* targets    = (const int*)d_in[19];
  float* out = (float*)d_out;                      // OUTPUT IS FLOAT32
  float* gate_out = out + (size_t)SB*TV;

  char* base = (char*)d_ws;
  size_t off = 0;
  auto take = [&](size_t bytes)->char*{
    char* p = base + off; off += (bytes + 255) & ~(size_t)255; return p;
  };
  ushort_t* Wih_hi = (ushort_t*)take((size_t)NP_G*KP*2);
  ushort_t* Wih_lo = (ushort_t*)take((size_t)NP_G*KP*2);
  ushort_t* Whh_hi = (ushort_t*)take((size_t)NP_G*KP*2);
  ushort_t* Whh_lo = (ushort_t*)take((size_t)NP_G*KP*2);
  ushort_t* hbf  = (ushort_t*)take((size_t)MP*KP*2);
  ushort_t* hbf2 = (ushort_t*)take((size_t)MP*KP*2);
  ushort_t* xbf  = (ushort_t*)take((size_t)MP*KP*2);
  ushort_t* xbf2 = (ushort_t*)take((size_t)MP*KP*2);
  float* hf    = (float*)take((size_t)SB*H_*4);
  float* xf    = (float*)take((size_t)SB*H_*4);
  float* ctx_s = (float*)take((size_t)SB*H_*4);
  float* ctx_u = (float*)take((size_t)SB*H_*4);
  float* p_s   = (float*)take((size_t)SB*L_*4);
  float* p_u   = (float*)take((size_t)SB*L_*4);
  float* gi    = (float*)take((size_t)SB*3*H_*4);
  float* gh    = (float*)take((size_t)SB*3*H_*4);
  float* sw_arr   = (float*)take(SB*4);
  float* ac_arr   = (float*)take(SB*4);
  float* bc_arr   = (float*)take(SB*4);
  float* pmaxw    = (float*)take((size_t)MP*NT_VOC*4);
  float* psumw    = (float*)take((size_t)MP*NT_VOC*4);
  // optional: bf16 emb copy (16.7 MB)
  int have_embp = (off + (size_t)NP_EMB*KP*2 + 512 <= ws_size) ? 1 : 0;
  ushort_t* embp = (ushort_t*)(have_embp ? take((size_t)NP_EMB*KP*2) : nullptr);
  // optional: transposed seq (B,H,L) x2 for coalesced attention scores
  size_t seqT_bytes = (size_t)B_*H_*L_*4;
  int have_seqT = (off + 2*((seqT_bytes+255)&~(size_t)255) <= ws_size) ? 1 : 0;
  float* seqT_s = (float*)(have_seqT ? take(seqT_bytes) : nullptr);
  float* seqT_u = (float*)(have_seqT ? take(seqT_bytes) : nullptr);

  int use_full = have_embp && have_seqT;

  if (use_full){
    setup_mega_kernel<<<2*TT_TILES + INIT_BLKS + 2*PS_BLKS + EC_BLKS, 256, 0, stream>>>(
        sys_H, user_H, seqT_s, seqT_u,
        slot_att, slot_emb, xf, xbf, xbf2, hbf, hbf2, hf,
        W_ih, Wih_hi, Wih_lo, W_hh, Whh_hi, Whh_lo, emb, embp);
    attend2_kernel<<<2*SB,256,0,stream>>>(sys_H, seqT_s, sys_musk,
                                          user_H, seqT_u, user_musk,
                                          hf, ctx_s, p_s, ctx_u, p_u);
    addh_kernel<<<(SB*H_+255)/256,256,0,stream>>>(ctx_s, ctx_u, hf, hbf, hbf2);

    for (int t=0; t<T_; t++){
      grugemm_kernel<<<dim3(NP_G/64, MP/64),256,0,stream>>>(xbf, xbf2, hbf, hbf2,
          Wih_hi, Wih_lo, Whh_hi, Whh_lo, gi, gh);
      gru_kernel<<<(SB*H_+255)/256,256,0,stream>>>(gi, gh, b_ih, b_hh, hf, hbf, hbf2);
      float* outp = out + (size_t)t*V_;   // f32 logits staged in-place in the t-slice
      mega_kernel<<<2*SB + NT_VOC*(MP/64),256,0,stream>>>(
          sys_H, seqT_s, sys_musk, user_H, seqT_u, user_musk,
          hf, ctx_s, p_s, ctx_u, p_u,
          hbf, embp, outp, pmaxw, psumw);
      final_kernel<<<SB,256,0,stream>>>(hf, ctx_s, ctx_u,
          Wr_w, Wr_b, Wc_w, Wc_b, Wg_w, Wg_b,
          pmaxw, psumw, p_s, p_u, story_sys, story_user,
          outp, gate_out, (t==0)?1:0,
          targets, emb, xf, xbf, xbf2, t, (t<T_-1)?1:0);
    }
  } else {
    // fallback: round-1 structure, no transposed seq / no bf16 emb copy
    padsplit_kernel<<<(NP_G*KP+255)/256,256,0,stream>>>(W_ih, Wih_hi, Wih_lo);
    padsplit_kernel<<<(NP_G*KP+255)/256,256,0,stream>>>(W_hh, Whh_hi, Whh_lo);
    init_kernel<<<(MP*KP+255)/256,256,0,stream>>>(slot_att, slot_emb, xf, xbf, xbf2, hbf, hbf2, hf);
    attend_kernel<<<SB,256,0,stream>>>(sys_H, sys_musk, hf, ctx_s, p_s);
    attend_kernel<<<SB,256,0,stream>>>(user_H, user_musk, hf, ctx_u, p_u);
    addh_kernel<<<(SB*H_+255)/256,256,0,stream>>>(ctx_s, ctx_u, hf, hbf, hbf2);
    for (int t=0; t<T_; t++){
      grugemm_kernel<<<dim3(NP_G/64, MP/64),256,0,stream>>>(xbf, xbf2, hbf, hbf2,
          Wih_hi, Wih_lo, Whh_hi, Whh_lo, gi, gh);
      gru_kernel<<<(SB*H_+255)/256,256,0,stream>>>(gi, gh, b_ih, b_hh, hf, hbf, hbf2);
      attend_kernel<<<SB,256,0,stream>>>(sys_H, sys_musk, hf, ctx_s, p_s);
      attend_kernel<<<SB,256,0,stream>>>(user_H, user_musk, hf, ctx_u, p_u);
      small_kernel<<<SB,256,0,stream>>>(hf, ctx_s, ctx_u, xf, Wr_w, Wr_b, Wc_w, Wc_b, Wg_w, Wg_b,
                                        sw_arr, ac_arr, bc_arr, gate_out, (t==0)?1:0);
      float* outp = out + (size_t)t*V_;
      vocab_gemm_f32b<<<dim3(NT_VOC, MP/64),256,0,stream>>>(hbf, emb, outp);
      softmax_scatter_kernel<<<SB,256,0,stream>>>(sw_arr, ac_arr, bc_arr, p_s, p_u,
                                                  story_sys, story_user, outp);
      if (t < T_-1)
        nextx_kernel<<<(SB*H_+255)/256,256,0,stream>>>(targets, emb, xf, xbf, xbf2, t);
    }
  }
}